// Round 1
// baseline (321.092 us; speedup 1.0000x reference)
//
#include <hip/hip_runtime.h>
#include <math.h>

#define HPX 128
#define WPX 128
#define HW  16384          // H*W
#define CCH 16             // channels
#define NLINES 81920       // 5 * H * W
#define NPTS 32
#define LOI_SIZE (NLINES * 512)   // 41,943,040 floats
#define SORT_N 8192

// workspace layout (bytes)
#define FEAT_T_OFF 0                         // 16384*16*4 = 1 MB
#define KEYS_OFF   1048576                   // 8192 * 8 = 64 KB
#define CTR_OFF    (1048576 + 65536)         // 4 B

// ---------------------------------------------------------------------------
// features (C,H,W) -> feat_t (H*W, C)  : makes each bilinear corner a
// contiguous 64B (16-channel) vector for the loi kernel.
// ---------------------------------------------------------------------------
__global__ __launch_bounds__(256) void transpose_feat(
        const float* __restrict__ feat, float* __restrict__ feat_t) {
    int tid = blockIdx.x * 256 + threadIdx.x;   // 0 .. 262143
    int pix = tid >> 4;
    int c   = tid & 15;
    feat_t[tid] = feat[c * HW + pix];           // write coalesced, reads L2-cached
}

// ---------------------------------------------------------------------------
// 3x3 NMS + compact survivors (val>0) into packed u64 keys:
//   key = float_bits(val) << 32 | (0xFFFFFFFF - idx)
// Descending u64 sort => descending value, ascending index tie-break
// (matches jax.lax.top_k stability).
// ---------------------------------------------------------------------------
__global__ __launch_bounds__(256) void nms_compact(
        const float* __restrict__ jloc,
        unsigned long long* __restrict__ keys,
        unsigned int* __restrict__ ctr) {
    int pix = blockIdx.x * 256 + threadIdx.x;
    if (pix >= HW) return;
    int y = pix >> 7, x = pix & 127;
    float a = jloc[pix];
    float m = a;
    #pragma unroll
    for (int dy = -1; dy <= 1; dy++) {
        #pragma unroll
        for (int dx = -1; dx <= 1; dx++) {
            int yy = y + dy, xx = x + dx;
            if (yy >= 0 && yy < HPX && xx >= 0 && xx < WPX) {
                m = fmaxf(m, jloc[yy * WPX + xx]);
            }
        }
    }
    if (a == m && a > 0.0f) {
        unsigned int slot = atomicAdd(ctr, 1u);
        if (slot < SORT_N) {
            unsigned int bits = __float_as_uint(a);
            keys[slot] = ((unsigned long long)bits << 32)
                       | (unsigned long long)(0xFFFFFFFFu - (unsigned int)pix);
        }
    }
}

// ---------------------------------------------------------------------------
// One-block bitonic sort (descending) over SORT_N u64 keys in LDS, then
// emit top-k junctions (x,y) and scores.
// ---------------------------------------------------------------------------
__global__ __launch_bounds__(1024) void sort_topk(
        const unsigned long long* __restrict__ keys_g,
        const float* __restrict__ joff,
        float* __restrict__ junc, float* __restrict__ scores, int topk) {
    __shared__ unsigned long long sk[SORT_N];   // 64 KB LDS
    int t = threadIdx.x;
    for (int i = t; i < SORT_N; i += 1024) sk[i] = keys_g[i];
    __syncthreads();
    for (int k = 2; k <= SORT_N; k <<= 1) {
        for (int j = k >> 1; j > 0; j >>= 1) {
            for (int i = t; i < SORT_N; i += 1024) {
                int ixj = i ^ j;
                if (ixj > i) {
                    unsigned long long a = sk[i], b = sk[ixj];
                    bool desc = ((i & k) == 0);
                    if (desc ? (a < b) : (a > b)) { sk[i] = b; sk[ixj] = a; }
                }
            }
            __syncthreads();
        }
    }
    if (t < topk) {
        unsigned long long kk = sk[t];
        float val = __uint_as_float((unsigned int)(kk >> 32));
        unsigned int idx = 0xFFFFFFFFu - (unsigned int)(kk & 0xFFFFFFFFull);
        float xo = joff[idx];        // joff[0][idx]
        float yo = joff[HW + idx];   // joff[1][idx]
        junc[2 * t]     = (float)(idx & 127) + xo + 0.5f;  // x
        junc[2 * t + 1] = (float)(idx >> 7)  + yo + 0.5f;  // y
        scores[t] = val;
    }
}

// ---------------------------------------------------------------------------
// Fused hafm_decoding + compute_loi_features.
// One thread = one (line, point). 16 channels per thread via 4x float4
// loads per bilinear corner from the (H,W,C)-transposed features.
// out[line*512 + c*32 + k]
// ---------------------------------------------------------------------------
__global__ __launch_bounds__(256) void loi_kernel(
        const float* __restrict__ md,
        const float* __restrict__ dis,
        const float* __restrict__ res,
        const float* __restrict__ feat_t,
        float* __restrict__ out) {
    int tid  = blockIdx.x * 256 + threadIdx.x;   // 0 .. 2,621,439
    int line = tid >> 5;
    int k    = tid & 31;
    int r    = line >> 14;        // 0..4
    int pix  = line & (HW - 1);
    int y0i  = pix >> 7, x0i = pix & 127;

    float md0 = md[pix], md1 = md[HW + pix], md2 = md[2 * HW + pix];
    float dv  = dis[pix], rv = res[pix];

    float dist = fminf(fmaxf(dv + rv * ((float)r - 2.0f), 0.0f), 1.0f);
    float d5   = dist * 5.0f;     // dist * DIST_THRESHOLD
    float md_un = (md0 - 0.5f) * 6.28318530717958647692f;  // (md-0.5)*2*pi
    float cs = cosf(md_un), ss = sinf(md_un);
    float y_st = tanf(md1 * 1.57079632679489661923f);      // tan(md1*pi/2)
    float y_ed = tanf(-md2 * 1.57079632679489661923f);     // tan(-md2*pi/2)

    float x0f = (float)x0i, y0f = (float)y0i;
    float xs = fminf(fmaxf((cs - ss * y_st) * d5 + x0f, 0.0f), 127.0f);
    float ys = fminf(fmaxf((ss + cs * y_st) * d5 + y0f, 0.0f), 127.0f);
    float xe = fminf(fmaxf((cs - ss * y_ed) * d5 + x0f, 0.0f), 127.0f);
    float ye = fminf(fmaxf((ss + cs * y_ed) * d5 + y0f, 0.0f), 127.0f);

    float t  = (float)k * (1.0f / 31.0f);      // tspan
    float px = xs * t + xe * (1.0f - t) - 0.5f;
    float py = ys * t + ye * (1.0f - t) - 0.5f;

    float px0 = fminf(fmaxf(floorf(px), 0.0f), 127.0f);
    float py0 = fminf(fmaxf(floorf(py), 0.0f), 127.0f);
    float px1 = fminf(px0 + 1.0f, 127.0f);
    float py1 = fminf(py0 + 1.0f, 127.0f);

    float wx1 = px - px0, wx0 = px1 - px;      // matches ref (can be <0/>1 at edges)
    float wy1 = py - py0, wy0 = py1 - py;
    float w00 = wy0 * wx0, w01 = wy0 * wx1;
    float w10 = wy1 * wx0, w11 = wy1 * wx1;

    int i00 = (((int)py0) * WPX + (int)px0) * CCH;
    int i01 = (((int)py0) * WPX + (int)px1) * CCH;
    int i10 = (((int)py1) * WPX + (int)px0) * CCH;
    int i11 = (((int)py1) * WPX + (int)px1) * CCH;

    const float4* f00 = (const float4*)(feat_t + i00);
    const float4* f01 = (const float4*)(feat_t + i01);
    const float4* f10 = (const float4*)(feat_t + i10);
    const float4* f11 = (const float4*)(feat_t + i11);

    float* ob = out + (size_t)line * 512 + k;
    #pragma unroll
    for (int j = 0; j < 4; j++) {
        float4 a = f00[j], b = f01[j], c4 = f10[j], d4 = f11[j];
        float4 acc;
        acc.x = a.x * w00 + b.x * w01 + c4.x * w10 + d4.x * w11;
        acc.y = a.y * w00 + b.y * w01 + c4.y * w10 + d4.y * w11;
        acc.z = a.z * w00 + b.z * w01 + c4.z * w10 + d4.z * w11;
        acc.w = a.w * w00 + b.w * w01 + c4.w * w10 + d4.w * w11;
        ob[(j * 4 + 0) * 32] = acc.x;
        ob[(j * 4 + 1) * 32] = acc.y;
        ob[(j * 4 + 2) * 32] = acc.z;
        ob[(j * 4 + 3) * 32] = acc.w;
    }
}

extern "C" void kernel_launch(void* const* d_in, const int* in_sizes, int n_in,
                              void* d_out, int out_size, void* d_ws, size_t ws_size,
                              hipStream_t stream) {
    const float* md   = (const float*)d_in[0];
    const float* dis  = (const float*)d_in[1];
    const float* res  = (const float*)d_in[2];
    const float* feat = (const float*)d_in[3];
    const float* jloc = (const float*)d_in[4];
    const float* joff = (const float*)d_in[5];
    // topk recovered from out_size (junctions 2k + scores k after loi)
    int topk = (out_size - LOI_SIZE) / 3;

    char* ws = (char*)d_ws;
    float* feat_t             = (float*)(ws + FEAT_T_OFF);
    unsigned long long* keys  = (unsigned long long*)(ws + KEYS_OFF);
    unsigned int* ctr         = (unsigned int*)(ws + CTR_OFF);

    float* out    = (float*)d_out;
    float* junc   = out + LOI_SIZE;
    float* scores = junc + 2 * topk;

    // zero keys + counter (ws is poisoned 0xAA before every launch)
    hipMemsetAsync(ws + KEYS_OFF, 0, SORT_N * 8 + 4, stream);

    transpose_feat<<<(HW * CCH) / 256, 256, 0, stream>>>(feat, feat_t);
    nms_compact  <<<HW / 256,        256, 0, stream>>>(jloc, keys, ctr);
    sort_topk    <<<1,              1024, 0, stream>>>(keys, joff, junc, scores, topk);
    loi_kernel   <<<(NLINES * NPTS) / 256, 256, 0, stream>>>(md, dis, res, feat_t, out);
}

// Round 2
// 228.884 us; speedup vs baseline: 1.4029x; 1.4029x over previous
//
#include <hip/hip_runtime.h>
#include <math.h>

#define HPX 128
#define WPX 128
#define HW  16384          // H*W
#define CCH 16             // channels
#define NLINES 81920       // 5 * H * W
#define NPTS 32
#define LOI_SIZE (NLINES * 512)   // 41,943,040 floats
#define SORT_N 8192
#define NBINS 4096
#define CAND 1024

// workspace layout (bytes)
#define FEAT_T_OFF 0                             // 1,048,576
#define LINES_OFF  1048576                       // 81920*16 = 1,310,720
#define KEYS_OFF   (1048576 + 1310720)           // 65,536
#define HIST_OFF   (KEYS_OFF + 65536)            // 16,384
#define CTR_OFF    (HIST_OFF + 16384)            // 4

// ---------------------------------------------------------------------------
// features (C,H,W) -> feat_t (H*W, C)
// ---------------------------------------------------------------------------
__global__ __launch_bounds__(256) void transpose_feat(
        const float* __restrict__ feat, float* __restrict__ feat_t) {
    int tid = blockIdx.x * 256 + threadIdx.x;   // 0 .. 262143
    int pix = tid >> 4;
    int c   = tid & 15;
    feat_t[tid] = feat[c * HW + pix];
}

// ---------------------------------------------------------------------------
// Per-line endpoint decode (all trig lives here, 81920 threads only).
// lines[line] = (xs, ys, xe, ye)
// ---------------------------------------------------------------------------
__global__ __launch_bounds__(256) void lines_kernel(
        const float* __restrict__ md,
        const float* __restrict__ dis,
        const float* __restrict__ res,
        float4* __restrict__ lines) {
    int line = blockIdx.x * 256 + threadIdx.x;   // 0 .. 81919
    int r    = line >> 14;        // 0..4
    int pix  = line & (HW - 1);
    int y0i  = pix >> 7, x0i = pix & 127;

    float md0 = md[pix], md1 = md[HW + pix], md2 = md[2 * HW + pix];
    float dv  = dis[pix], rv = res[pix];

    float dist = fminf(fmaxf(dv + rv * ((float)r - 2.0f), 0.0f), 1.0f);
    float d5   = dist * 5.0f;
    float md_un = (md0 - 0.5f) * 6.28318530717958647692f;
    float cs = cosf(md_un), ss = sinf(md_un);
    float y_st = tanf(md1 * 1.57079632679489661923f);
    float y_ed = tanf(-md2 * 1.57079632679489661923f);

    float x0f = (float)x0i, y0f = (float)y0i;
    float4 ep;
    ep.x = fminf(fmaxf((cs - ss * y_st) * d5 + x0f, 0.0f), 127.0f);  // xs
    ep.y = fminf(fmaxf((ss + cs * y_st) * d5 + y0f, 0.0f), 127.0f);  // ys
    ep.z = fminf(fmaxf((cs - ss * y_ed) * d5 + x0f, 0.0f), 127.0f);  // xe
    ep.w = fminf(fmaxf((ss + cs * y_ed) * d5 + y0f, 0.0f), 127.0f);  // ye
    lines[line] = ep;
}

// ---------------------------------------------------------------------------
// 3x3 NMS + compact survivors + 4096-bin value histogram.
// key = float_bits(val)<<32 | (0xFFFFFFFF - idx)  (desc sort => topk order)
// ---------------------------------------------------------------------------
__global__ __launch_bounds__(256) void nms_compact(
        const float* __restrict__ jloc,
        unsigned long long* __restrict__ keys,
        unsigned int* __restrict__ hist,
        unsigned int* __restrict__ ctr) {
    int pix = blockIdx.x * 256 + threadIdx.x;
    if (pix >= HW) return;
    int y = pix >> 7, x = pix & 127;
    float a = jloc[pix];
    float m = a;
    #pragma unroll
    for (int dy = -1; dy <= 1; dy++) {
        #pragma unroll
        for (int dx = -1; dx <= 1; dx++) {
            int yy = y + dy, xx = x + dx;
            if (yy >= 0 && yy < HPX && xx >= 0 && xx < WPX) {
                m = fmaxf(m, jloc[yy * WPX + xx]);
            }
        }
    }
    if (a == m && a > 0.0f) {
        unsigned int slot = atomicAdd(ctr, 1u);
        if (slot < SORT_N) {
            unsigned int bits = __float_as_uint(a);
            keys[slot] = ((unsigned long long)bits << 32)
                       | (unsigned long long)(0xFFFFFFFFu - (unsigned int)pix);
        }
        int bin = min(NBINS - 1, (int)(a * (float)NBINS));
        atomicAdd(&hist[bin], 1u);
    }
}

// ---------------------------------------------------------------------------
// Single-block top-k: suffix-scan histogram -> threshold bin T -> compact
// candidates (bin >= T, guaranteed >= topk of them) -> bitonic sort 1024 ->
// emit junctions + scores.
// ---------------------------------------------------------------------------
__global__ __launch_bounds__(1024) void select_topk(
        const unsigned long long* __restrict__ keys_g,
        const unsigned int* __restrict__ ctr,
        const unsigned int* __restrict__ hist,
        const float* __restrict__ joff,
        float* __restrict__ junc, float* __restrict__ scores, int topk) {
    __shared__ unsigned int h[NBINS];            // 16 KB
    __shared__ unsigned long long cand[CAND];    // 8 KB
    __shared__ unsigned int scount;
    __shared__ int Ts;
    int t = threadIdx.x;

    #pragma unroll
    for (int r = 0; r < 4; r++) h[t + r * 1024] = hist[t + r * 1024];
    if (t == 0) { scount = 0; Ts = 0; }
    __syncthreads();

    // suffix sum: h[b] := sum_{b' >= b} h[b']   (Hillis-Steele, 12 passes)
    for (int off = 1; off < NBINS; off <<= 1) {
        unsigned int v[4];
        #pragma unroll
        for (int r = 0; r < 4; r++) {
            int i = t + r * 1024;
            v[r] = (i + off < NBINS) ? h[i + off] : 0u;
        }
        __syncthreads();
        #pragma unroll
        for (int r = 0; r < 4; r++) h[t + r * 1024] += v[r];
        __syncthreads();
    }

    // threshold bin T: h[T] >= topk, h[T+1] < topk (unique crossing)
    #pragma unroll
    for (int r = 0; r < 4; r++) {
        int b = t + r * 1024;
        unsigned int sb = h[b];
        unsigned int sn = (b + 1 < NBINS) ? h[b + 1] : 0u;
        if (sb >= (unsigned int)topk && sn < (unsigned int)topk) Ts = b;
    }
    __syncthreads();
    int T = Ts;

    // compact candidates
    int n = min(ctr[0], (unsigned int)SORT_N);
    for (int i = t; i < n; i += 1024) {
        unsigned long long kk = keys_g[i];
        float val = __uint_as_float((unsigned int)(kk >> 32));
        int bin = min(NBINS - 1, (int)(val * (float)NBINS));
        if (bin >= T) {
            unsigned int p = atomicAdd(&scount, 1u);
            if (p < CAND) cand[p] = kk;
        }
    }
    __syncthreads();
    unsigned int sc = min(scount, (unsigned int)CAND);
    if (t >= (int)sc) cand[t] = 0ull;           // pad
    __syncthreads();

    // bitonic sort 1024 descending
    for (int k = 2; k <= CAND; k <<= 1) {
        for (int j = k >> 1; j > 0; j >>= 1) {
            int ixj = t ^ j;
            if (ixj > t) {
                unsigned long long a = cand[t], b = cand[ixj];
                bool desc = ((t & k) == 0);
                if (desc ? (a < b) : (a > b)) { cand[t] = b; cand[ixj] = a; }
            }
            __syncthreads();
        }
    }

    if (t < topk) {
        unsigned long long kk = cand[t];
        float val = __uint_as_float((unsigned int)(kk >> 32));
        unsigned int idx = 0xFFFFFFFFu - (unsigned int)(kk & 0xFFFFFFFFull);
        if (idx >= HW) idx = 0;                  // pad guard (unreachable here)
        float xo = joff[idx];
        float yo = joff[HW + idx];
        junc[2 * t]     = (float)(idx & 127) + xo + 0.5f;
        junc[2 * t + 1] = (float)(idx >> 7)  + yo + 0.5f;
        scores[t] = val;
    }
}

// ---------------------------------------------------------------------------
// LOI: one thread = (line, k-quad). 4 sample points x 16 channels;
// 16 coalesced float4 stores. No trig here (reads lines[]).
// ---------------------------------------------------------------------------
__global__ __launch_bounds__(256) void loi_kernel(
        const float4* __restrict__ lines,
        const float* __restrict__ feat_t,
        float* __restrict__ out) {
    int tid  = blockIdx.x * 256 + threadIdx.x;   // 0 .. 655,359
    int kq   = tid & 7;
    int line = tid >> 3;

    float4 ep = lines[line];
    float v[64];                                  // [c][p], static-indexed

    #pragma unroll
    for (int p = 0; p < 4; ++p) {
        int k = kq * 4 + p;
        float tk = (float)k * (1.0f / 31.0f);
        float px = ep.x * tk + ep.z * (1.0f - tk) - 0.5f;
        float py = ep.y * tk + ep.w * (1.0f - tk) - 0.5f;

        float px0 = fminf(fmaxf(floorf(px), 0.0f), 127.0f);
        float py0 = fminf(fmaxf(floorf(py), 0.0f), 127.0f);
        float px1 = fminf(px0 + 1.0f, 127.0f);
        float py1 = fminf(py0 + 1.0f, 127.0f);

        float wx1 = px - px0, wx0 = px1 - px;
        float wy1 = py - py0, wy0 = py1 - py;
        float w00 = wy0 * wx0, w01 = wy0 * wx1;
        float w10 = wy1 * wx0, w11 = wy1 * wx1;

        int b00 = (((int)py0) * WPX + (int)px0) * 4;   // float4 index
        int b01 = (((int)py0) * WPX + (int)px1) * 4;
        int b10 = (((int)py1) * WPX + (int)px0) * 4;
        int b11 = (((int)py1) * WPX + (int)px1) * 4;

        const float4* f4 = (const float4*)feat_t;
        #pragma unroll
        for (int cq = 0; cq < 4; ++cq) {
            float4 a = f4[b00 + cq], b = f4[b01 + cq];
            float4 c = f4[b10 + cq], d = f4[b11 + cq];
            v[(cq * 4 + 0) * 4 + p] = a.x * w00 + b.x * w01 + c.x * w10 + d.x * w11;
            v[(cq * 4 + 1) * 4 + p] = a.y * w00 + b.y * w01 + c.y * w10 + d.y * w11;
            v[(cq * 4 + 2) * 4 + p] = a.z * w00 + b.z * w01 + c.z * w10 + d.z * w11;
            v[(cq * 4 + 3) * 4 + p] = a.w * w00 + b.w * w01 + c.w * w10 + d.w * w11;
        }
    }

    float* ob = out + (size_t)line * 512 + kq * 4;
    #pragma unroll
    for (int c = 0; c < 16; ++c) {
        float4 st = make_float4(v[c * 4 + 0], v[c * 4 + 1], v[c * 4 + 2], v[c * 4 + 3]);
        *(float4*)(ob + c * 32) = st;
    }
}

extern "C" void kernel_launch(void* const* d_in, const int* in_sizes, int n_in,
                              void* d_out, int out_size, void* d_ws, size_t ws_size,
                              hipStream_t stream) {
    const float* md   = (const float*)d_in[0];
    const float* dis  = (const float*)d_in[1];
    const float* res  = (const float*)d_in[2];
    const float* feat = (const float*)d_in[3];
    const float* jloc = (const float*)d_in[4];
    const float* joff = (const float*)d_in[5];
    int topk = (out_size - LOI_SIZE) / 3;

    char* ws = (char*)d_ws;
    float* feat_t             = (float*)(ws + FEAT_T_OFF);
    float4* lines             = (float4*)(ws + LINES_OFF);
    unsigned long long* keys  = (unsigned long long*)(ws + KEYS_OFF);
    unsigned int* hist        = (unsigned int*)(ws + HIST_OFF);
    unsigned int* ctr         = (unsigned int*)(ws + CTR_OFF);

    float* out    = (float*)d_out;
    float* junc   = out + LOI_SIZE;
    float* scores = junc + 2 * topk;

    // zero hist + ctr (contiguous)
    hipMemsetAsync(ws + HIST_OFF, 0, NBINS * 4 + 4, stream);

    transpose_feat<<<(HW * CCH) / 256, 256, 0, stream>>>(feat, feat_t);
    lines_kernel <<<NLINES / 256,      256, 0, stream>>>(md, dis, res, lines);
    nms_compact  <<<HW / 256,          256, 0, stream>>>(jloc, keys, hist, ctr);
    select_topk  <<<1,                1024, 0, stream>>>(keys, ctr, hist, joff, junc, scores, topk);
    loi_kernel   <<<(NLINES * 8) / 256, 256, 0, stream>>>(lines, feat_t, out);
}